// Round 1
// baseline (1580.294 us; speedup 1.0000x reference)
//
#include <hip/hip_runtime.h>

#define D 64
#define H 256

// ---------------------------------------------------------------------------
// Kernel 1: rst = feat  (EPS = 0, so rst = (1+eps)*feat = feat)
// ---------------------------------------------------------------------------
__global__ void copy_feat_kernel(const float* __restrict__ feat,
                                 float* __restrict__ rst, int n4) {
    int i = blockIdx.x * blockDim.x + threadIdx.x;
    if (i < n4) {
        reinterpret_cast<float4*>(rst)[i] =
            reinterpret_cast<const float4*>(feat)[i];
    }
}

// ---------------------------------------------------------------------------
// Kernel 2: rst[dst[e]] += feat[src[e]]   (segment_sum scatter)
// 16 threads per edge, each handles one float4 chunk (4 atomics).
// ---------------------------------------------------------------------------
__global__ void scatter_add_kernel(const float* __restrict__ feat,
                                   const int* __restrict__ src,
                                   const int* __restrict__ dst,
                                   float* rst, int E) {
    int gid = blockIdx.x * blockDim.x + threadIdx.x;
    int e  = gid >> 4;
    if (e >= E) return;
    int d4 = (gid & 15) << 2;
    int s = src[e];
    int t = dst[e];
    float4 v = *reinterpret_cast<const float4*>(&feat[s * D + d4]);
    float* p = &rst[t * D + d4];
    atomicAdd(p + 0, v.x);
    atomicAdd(p + 1, v.y);
    atomicAdd(p + 2, v.z);
    atomicAdd(p + 3, v.w);
}

// ---------------------------------------------------------------------------
// Kernel 3: out = relu(rst @ W1 + b1) @ W2 + b2
// One node per thread. Weights staged in LDS (W1 transposed so that both
// W1-column and W2-row reads are contiguous float4, wave-uniform broadcast).
// rst/out may alias: each thread reads its full row before writing it.
// ---------------------------------------------------------------------------
__global__ __launch_bounds__(512) void mlp_kernel(
        const float* rst,
        const float* __restrict__ W1, const float* __restrict__ b1,
        const float* __restrict__ W2, const float* __restrict__ b2,
        float* out, int n) {
    __shared__ float sW1t[H * D];   // 64 KiB, sW1t[j*D + d] = W1[d*H + j]
    __shared__ float sW2 [H * D];   // 64 KiB, row-major [H][D]
    __shared__ float sb1[H];
    __shared__ float sb2[D];

    // cooperative staging
    for (int i = threadIdx.x; i < D * H; i += 512) {
        int d = i >> 8;          // i / H
        int j = i & (H - 1);     // i % H
        sW1t[j * D + d] = W1[i];
        sW2[i] = W2[i];
    }
    if (threadIdx.x < H) sb1[threadIdx.x] = b1[threadIdx.x];
    if (threadIdx.x < D) sb2[threadIdx.x] = b2[threadIdx.x];
    __syncthreads();

    int node = blockIdx.x * 512 + threadIdx.x;
    if (node >= n) return;

    // load this node's rst row into registers (16 x float4)
    float x[D];
    const float4* xr = reinterpret_cast<const float4*>(&rst[node * D]);
#pragma unroll
    for (int d4 = 0; d4 < D / 4; ++d4) {
        float4 v = xr[d4];
        x[d4 * 4 + 0] = v.x; x[d4 * 4 + 1] = v.y;
        x[d4 * 4 + 2] = v.z; x[d4 * 4 + 3] = v.w;
    }

    float acc[D];
#pragma unroll
    for (int d = 0; d < D; ++d) acc[d] = sb2[d];

    for (int j = 0; j < H; ++j) {
        float h = sb1[j];
        const float4* w1 = reinterpret_cast<const float4*>(&sW1t[j * D]);
#pragma unroll
        for (int d4 = 0; d4 < D / 4; ++d4) {
            float4 w = w1[d4];
            h += x[d4 * 4 + 0] * w.x + x[d4 * 4 + 1] * w.y +
                 x[d4 * 4 + 2] * w.z + x[d4 * 4 + 3] * w.w;
        }
        h = fmaxf(h, 0.0f);
        const float4* w2 = reinterpret_cast<const float4*>(&sW2[j * D]);
#pragma unroll
        for (int d4 = 0; d4 < D / 4; ++d4) {
            float4 w = w2[d4];
            acc[d4 * 4 + 0] += h * w.x; acc[d4 * 4 + 1] += h * w.y;
            acc[d4 * 4 + 2] += h * w.z; acc[d4 * 4 + 3] += h * w.w;
        }
    }

    float4* op = reinterpret_cast<float4*>(&out[node * D]);
#pragma unroll
    for (int d4 = 0; d4 < D / 4; ++d4) {
        float4 v;
        v.x = acc[d4 * 4 + 0]; v.y = acc[d4 * 4 + 1];
        v.z = acc[d4 * 4 + 2]; v.w = acc[d4 * 4 + 3];
        op[d4] = v;
    }
}

// ---------------------------------------------------------------------------
extern "C" void kernel_launch(void* const* d_in, const int* in_sizes, int n_in,
                              void* d_out, int out_size, void* d_ws, size_t ws_size,
                              hipStream_t stream) {
    const float* feat = (const float*)d_in[0];
    const float* W1   = (const float*)d_in[1];
    const float* b1   = (const float*)d_in[2];
    const float* W2   = (const float*)d_in[3];
    const float* b2   = (const float*)d_in[4];
    const int*   src  = (const int*)d_in[5];
    const int*   dst  = (const int*)d_in[6];
    float* buf = (float*)d_out;   // used as rst, then overwritten with out

    int n = in_sizes[0] / D;      // 100000 nodes
    int E = in_sizes[5];          // 1600000 edges

    // 1) rst = feat
    int n4 = n * D / 4;
    copy_feat_kernel<<<(n4 + 255) / 256, 256, 0, stream>>>(feat, buf, n4);

    // 2) rst[dst] += feat[src]
    int threads = E * 16;
    scatter_add_kernel<<<(threads + 255) / 256, 256, 0, stream>>>(
        feat, src, dst, buf, E);

    // 3) out = relu(rst @ W1 + b1) @ W2 + b2   (in place over buf)
    mlp_kernel<<<(n + 511) / 512, 512, 0, stream>>>(
        buf, W1, b1, W2, b2, buf, n);
}

// Round 2
// 469.848 us; speedup vs baseline: 3.3634x; 3.3634x over previous
//
#include <hip/hip_runtime.h>

#define D 64
#define H 256

// ===========================================================================
// CSR build: zero -> histogram -> scan -> fill
// ===========================================================================
__global__ void zero_int_kernel(int* __restrict__ p, int n) {
    int i = blockIdx.x * blockDim.x + threadIdx.x;
    if (i < n) p[i] = 0;
}

__global__ void hist_kernel(const int* __restrict__ dst, int* __restrict__ deg, int E) {
    int e = blockIdx.x * blockDim.x + threadIdx.x;
    if (e < E) atomicAdd(&deg[dst[e]], 1);
}

// Block-level exclusive scan: 256 threads x 4 elems = 1024 per block.
__global__ void scan_blocks_kernel(const int* __restrict__ deg,
                                   int* __restrict__ off,
                                   int* __restrict__ bsums, int n) {
    __shared__ int s[256];
    int tid = threadIdx.x;
    int base = blockIdx.x * 1024 + tid * 4;
    int v0 = (base + 0 < n) ? deg[base + 0] : 0;
    int v1 = (base + 1 < n) ? deg[base + 1] : 0;
    int v2 = (base + 2 < n) ? deg[base + 2] : 0;
    int v3 = (base + 3 < n) ? deg[base + 3] : 0;
    int tot = v0 + v1 + v2 + v3;
    s[tid] = tot;
    __syncthreads();
    for (int o = 1; o < 256; o <<= 1) {
        int t = (tid >= o) ? s[tid - o] : 0;
        __syncthreads();
        s[tid] += t;
        __syncthreads();
    }
    int excl = s[tid] - tot;   // exclusive offset of this thread within block
    if (base + 0 < n) off[base + 0] = excl;
    if (base + 1 < n) off[base + 1] = excl + v0;
    if (base + 2 < n) off[base + 2] = excl + v0 + v1;
    if (base + 3 < n) off[base + 3] = excl + v0 + v1 + v2;
    if (tid == 255) bsums[blockIdx.x] = s[255];
}

// Single-block exclusive scan of block sums (handles nb up to anything, looped).
__global__ void scan_sums_kernel(int* __restrict__ bsums, int nb) {
    __shared__ int s[256];
    int tid = threadIdx.x;
    int carry = 0;
    for (int base = 0; base < nb; base += 256) {
        int i = base + tid;
        int v = (i < nb) ? bsums[i] : 0;
        s[tid] = v;
        __syncthreads();
        for (int o = 1; o < 256; o <<= 1) {
            int t = (tid >= o) ? s[tid - o] : 0;
            __syncthreads();
            s[tid] += t;
            __syncthreads();
        }
        if (i < nb) bsums[i] = carry + s[tid] - v;   // exclusive
        int total = s[255];
        __syncthreads();
        carry += total;
    }
}

// Add block offsets; also produce cursor copy and off[n] = E.
__global__ void scan_finish_kernel(int* __restrict__ off,
                                   int* __restrict__ cursor,
                                   const int* __restrict__ bsums,
                                   int n, int E) {
    int i = blockIdx.x * blockDim.x + threadIdx.x;
    if (i < n) {
        int v = off[i] + bsums[i >> 10];   // 1024 elems per scan block
        off[i] = v;
        cursor[i] = v;
    }
    if (i == 0) off[n] = E;
}

__global__ void fill_kernel(const int* __restrict__ src,
                            const int* __restrict__ dst,
                            int* __restrict__ cursor,
                            int* __restrict__ csr_src, int E) {
    int e = blockIdx.x * blockDim.x + threadIdx.x;
    if (e < E) {
        int pos = atomicAdd(&cursor[dst[e]], 1);
        csr_src[pos] = src[e];
    }
}

// ===========================================================================
// Gather: rst[n] = feat[n] + sum_{i in off[n]..off[n+1]} feat[csr_src[i]]
// 16 lanes per node, each lane owns one float4 chunk of the row.
// ===========================================================================
__global__ void gather_kernel(const float* __restrict__ feat,
                              const int* __restrict__ off,
                              const int* __restrict__ csr_src,
                              float* __restrict__ rst, int n) {
    int gid = blockIdx.x * blockDim.x + threadIdx.x;
    int node = gid >> 4;
    if (node >= n) return;
    int g = gid & 15;    // float4 chunk index

    const float4* f4 = reinterpret_cast<const float4*>(feat);
    float4 acc = f4[node * 16 + g];       // (1+eps)*feat, eps=0

    int s = off[node];
    int e = off[node + 1];
    for (int i = s; i < e; ++i) {
        int u = csr_src[i];
        float4 v = f4[u * 16 + g];
        acc.x += v.x; acc.y += v.y; acc.z += v.z; acc.w += v.w;
    }
    reinterpret_cast<float4*>(rst)[node * 16 + g] = acc;
}

// ===========================================================================
// Fallback scatter (atomics) — used only if workspace is too small.
// ===========================================================================
__global__ void copy_feat_kernel(const float* __restrict__ feat,
                                 float* __restrict__ rst, int n4) {
    int i = blockIdx.x * blockDim.x + threadIdx.x;
    if (i < n4) {
        reinterpret_cast<float4*>(rst)[i] =
            reinterpret_cast<const float4*>(feat)[i];
    }
}

__global__ void scatter_add_kernel(const float* __restrict__ feat,
                                   const int* __restrict__ src,
                                   const int* __restrict__ dst,
                                   float* rst, int E) {
    int gid = blockIdx.x * blockDim.x + threadIdx.x;
    int e  = gid >> 4;
    if (e >= E) return;
    int d4 = (gid & 15) << 2;
    int s = src[e];
    int t = dst[e];
    float4 v = *reinterpret_cast<const float4*>(&feat[s * D + d4]);
    float* p = &rst[t * D + d4];
    atomicAdd(p + 0, v.x);
    atomicAdd(p + 1, v.y);
    atomicAdd(p + 2, v.z);
    atomicAdd(p + 3, v.w);
}

// ===========================================================================
// MLP: out = relu(rst @ W1 + b1) @ W2 + b2, one node per thread,
// weights staged in LDS (W1 transposed for contiguous broadcast reads).
// ===========================================================================
__global__ __launch_bounds__(512) void mlp_kernel(
        const float* rst,
        const float* __restrict__ W1, const float* __restrict__ b1,
        const float* __restrict__ W2, const float* __restrict__ b2,
        float* out, int n) {
    __shared__ float sW1t[H * D];   // sW1t[j*D + d] = W1[d*H + j]
    __shared__ float sW2 [H * D];   // row-major [H][D]
    __shared__ float sb1[H];
    __shared__ float sb2[D];

    for (int i = threadIdx.x; i < D * H; i += 512) {
        int d = i >> 8;
        int j = i & (H - 1);
        sW1t[j * D + d] = W1[i];
        sW2[i] = W2[i];
    }
    if (threadIdx.x < H) sb1[threadIdx.x] = b1[threadIdx.x];
    if (threadIdx.x < D) sb2[threadIdx.x] = b2[threadIdx.x];
    __syncthreads();

    int node = blockIdx.x * 512 + threadIdx.x;
    if (node >= n) return;

    float x[D];
    const float4* xr = reinterpret_cast<const float4*>(&rst[node * D]);
#pragma unroll
    for (int d4 = 0; d4 < D / 4; ++d4) {
        float4 v = xr[d4];
        x[d4 * 4 + 0] = v.x; x[d4 * 4 + 1] = v.y;
        x[d4 * 4 + 2] = v.z; x[d4 * 4 + 3] = v.w;
    }

    float acc[D];
#pragma unroll
    for (int d = 0; d < D; ++d) acc[d] = sb2[d];

    for (int j = 0; j < H; ++j) {
        float h = sb1[j];
        const float4* w1 = reinterpret_cast<const float4*>(&sW1t[j * D]);
#pragma unroll
        for (int d4 = 0; d4 < D / 4; ++d4) {
            float4 w = w1[d4];
            h += x[d4 * 4 + 0] * w.x + x[d4 * 4 + 1] * w.y +
                 x[d4 * 4 + 2] * w.z + x[d4 * 4 + 3] * w.w;
        }
        h = fmaxf(h, 0.0f);
        const float4* w2 = reinterpret_cast<const float4*>(&sW2[j * D]);
#pragma unroll
        for (int d4 = 0; d4 < D / 4; ++d4) {
            float4 w = w2[d4];
            acc[d4 * 4 + 0] += h * w.x; acc[d4 * 4 + 1] += h * w.y;
            acc[d4 * 4 + 2] += h * w.z; acc[d4 * 4 + 3] += h * w.w;
        }
    }

    float4* op = reinterpret_cast<float4*>(&out[node * D]);
#pragma unroll
    for (int d4 = 0; d4 < D / 4; ++d4) {
        float4 v;
        v.x = acc[d4 * 4 + 0]; v.y = acc[d4 * 4 + 1];
        v.z = acc[d4 * 4 + 2]; v.w = acc[d4 * 4 + 3];
        op[d4] = v;
    }
}

// ===========================================================================
extern "C" void kernel_launch(void* const* d_in, const int* in_sizes, int n_in,
                              void* d_out, int out_size, void* d_ws, size_t ws_size,
                              hipStream_t stream) {
    const float* feat = (const float*)d_in[0];
    const float* W1   = (const float*)d_in[1];
    const float* b1   = (const float*)d_in[2];
    const float* W2   = (const float*)d_in[3];
    const float* b2   = (const float*)d_in[4];
    const int*   src  = (const int*)d_in[5];
    const int*   dst  = (const int*)d_in[6];
    float* buf = (float*)d_out;   // rst, then out (in place)

    int n = in_sizes[0] / D;      // nodes
    int E = in_sizes[5];          // edges

    // workspace layout (ints)
    int nb = (n + 1023) / 1024;                 // scan blocks
    size_t need = (size_t)(n          /*deg->off staging uses off only*/
                 + (n + 1)            /*off*/
                 + n                  /*cursor*/
                 + ((nb + 255) & ~255)/*bsums padded*/
                 + E) * sizeof(int);

    if (ws_size >= need) {
        int* deg    = (int*)d_ws;
        int* off    = deg + n;
        int* cursor = off + (n + 1);
        int* bsums  = cursor + n;
        int* csr    = bsums + ((nb + 255) & ~255);

        zero_int_kernel<<<(n + 255) / 256, 256, 0, stream>>>(deg, n);
        hist_kernel<<<(E + 255) / 256, 256, 0, stream>>>(dst, deg, E);
        scan_blocks_kernel<<<nb, 256, 0, stream>>>(deg, off, bsums, n);
        scan_sums_kernel<<<1, 256, 0, stream>>>(bsums, nb);
        scan_finish_kernel<<<(n + 255) / 256, 256, 0, stream>>>(off, cursor, bsums, n, E);
        fill_kernel<<<(E + 255) / 256, 256, 0, stream>>>(src, dst, cursor, csr, E);

        int gthreads = n * 16;
        gather_kernel<<<(gthreads + 255) / 256, 256, 0, stream>>>(feat, off, csr, buf, n);
    } else {
        // fallback: atomic scatter
        int n4 = n * D / 4;
        copy_feat_kernel<<<(n4 + 255) / 256, 256, 0, stream>>>(feat, buf, n4);
        int threads = E * 16;
        scatter_add_kernel<<<(threads + 255) / 256, 256, 0, stream>>>(feat, src, dst, buf, E);
    }

    mlp_kernel<<<(n + 511) / 512, 512, 0, stream>>>(buf, W1, b1, W2, b2, buf, n);
}

// Round 3
// 272.013 us; speedup vs baseline: 5.8096x; 1.7273x over previous
//
#include <hip/hip_runtime.h>

#define D 64
#define H 256

typedef __bf16 bf16x8 __attribute__((ext_vector_type(8)));
typedef float f32x16 __attribute__((ext_vector_type(16)));
typedef unsigned int uint4v __attribute__((ext_vector_type(4)));

__device__ inline unsigned pack_bf16x2(float a, float b) {
    unsigned short ua = __builtin_bit_cast(unsigned short, (__bf16)a);
    unsigned short ub = __builtin_bit_cast(unsigned short, (__bf16)b);
    return (unsigned)ua | ((unsigned)ub << 16);
}

// swap lower-32-lane half of x with ... returns {lo_combined, hi_combined}:
// out0[l<32]=x[l], out0[l>=32]=y[l-32]; out1[l<32]=x[l+32], out1[l>=32]=y[l]
__device__ inline void lane32_swap(unsigned x, unsigned y, unsigned& o0, unsigned& o1) {
#if __has_builtin(__builtin_amdgcn_permlane32_swap)
    typedef unsigned int uint2v __attribute__((ext_vector_type(2)));
    uint2v r = __builtin_amdgcn_permlane32_swap(x, y, false, false);
    o0 = r.x; o1 = r.y;
#else
    unsigned xs = __shfl_xor((int)x, 32, 64);
    unsigned ys = __shfl_xor((int)y, 32, 64);
    bool hi = (threadIdx.x & 32) != 0;
    o0 = hi ? ys : x;
    o1 = hi ? y : xs;
#endif
}

// ===========================================================================
// CSR build: zero -> histogram -> scan -> fill
// ===========================================================================
__global__ void zero_int_kernel(int* __restrict__ p, int n) {
    int i = blockIdx.x * blockDim.x + threadIdx.x;
    if (i < n) p[i] = 0;
}

__global__ void hist_kernel(const int* __restrict__ dst, int* __restrict__ deg, int E) {
    int e = blockIdx.x * blockDim.x + threadIdx.x;
    if (e < E) atomicAdd(&deg[dst[e]], 1);
}

__global__ void scan_blocks_kernel(const int* __restrict__ deg,
                                   int* __restrict__ off,
                                   int* __restrict__ bsums, int n) {
    __shared__ int s[256];
    int tid = threadIdx.x;
    int base = blockIdx.x * 1024 + tid * 4;
    int v0 = (base + 0 < n) ? deg[base + 0] : 0;
    int v1 = (base + 1 < n) ? deg[base + 1] : 0;
    int v2 = (base + 2 < n) ? deg[base + 2] : 0;
    int v3 = (base + 3 < n) ? deg[base + 3] : 0;
    int tot = v0 + v1 + v2 + v3;
    s[tid] = tot;
    __syncthreads();
    for (int o = 1; o < 256; o <<= 1) {
        int t = (tid >= o) ? s[tid - o] : 0;
        __syncthreads();
        s[tid] += t;
        __syncthreads();
    }
    int excl = s[tid] - tot;
    if (base + 0 < n) off[base + 0] = excl;
    if (base + 1 < n) off[base + 1] = excl + v0;
    if (base + 2 < n) off[base + 2] = excl + v0 + v1;
    if (base + 3 < n) off[base + 3] = excl + v0 + v1 + v2;
    if (tid == 255) bsums[blockIdx.x] = s[255];
}

__global__ void scan_sums_kernel(int* __restrict__ bsums, int nb) {
    __shared__ int s[256];
    int tid = threadIdx.x;
    int carry = 0;
    for (int base = 0; base < nb; base += 256) {
        int i = base + tid;
        int v = (i < nb) ? bsums[i] : 0;
        s[tid] = v;
        __syncthreads();
        for (int o = 1; o < 256; o <<= 1) {
            int t = (tid >= o) ? s[tid - o] : 0;
            __syncthreads();
            s[tid] += t;
            __syncthreads();
        }
        if (i < nb) bsums[i] = carry + s[tid] - v;
        int total = s[255];
        __syncthreads();
        carry += total;
    }
}

__global__ void scan_finish_kernel(int* __restrict__ off,
                                   int* __restrict__ cursor,
                                   const int* __restrict__ bsums,
                                   int n, int E) {
    int i = blockIdx.x * blockDim.x + threadIdx.x;
    if (i < n) {
        int v = off[i] + bsums[i >> 10];
        off[i] = v;
        cursor[i] = v;
    }
    if (i == 0) off[n] = E;
}

__global__ void fill_kernel(const int* __restrict__ src,
                            const int* __restrict__ dst,
                            int* __restrict__ cursor,
                            int* __restrict__ csr_src, int E) {
    int e = blockIdx.x * blockDim.x + threadIdx.x;
    if (e < E) {
        int pos = atomicAdd(&cursor[dst[e]], 1);
        csr_src[pos] = src[e];
    }
}

// ===========================================================================
// Gather: rst[n] = feat[n] + sum_neighbors, 16 lanes/node, 4x unrolled
// ===========================================================================
__global__ void gather_kernel(const float* __restrict__ feat,
                              const int* __restrict__ off,
                              const int* __restrict__ csr_src,
                              float* __restrict__ rst, int n) {
    int gid = blockIdx.x * blockDim.x + threadIdx.x;
    int node = gid >> 4;
    if (node >= n) return;
    int g = gid & 15;

    const float4* f4 = reinterpret_cast<const float4*>(feat);
    float4 acc = f4[node * 16 + g];

    int s = off[node];
    int e = off[node + 1];
    int i = s;
    for (; i + 4 <= e; i += 4) {
        int u0 = csr_src[i + 0];
        int u1 = csr_src[i + 1];
        int u2 = csr_src[i + 2];
        int u3 = csr_src[i + 3];
        float4 v0 = f4[u0 * 16 + g];
        float4 v1 = f4[u1 * 16 + g];
        float4 v2 = f4[u2 * 16 + g];
        float4 v3 = f4[u3 * 16 + g];
        acc.x += (v0.x + v1.x) + (v2.x + v3.x);
        acc.y += (v0.y + v1.y) + (v2.y + v3.y);
        acc.z += (v0.z + v1.z) + (v2.z + v3.z);
        acc.w += (v0.w + v1.w) + (v2.w + v3.w);
    }
    for (; i < e; ++i) {
        int u = csr_src[i];
        float4 v = f4[u * 16 + g];
        acc.x += v.x; acc.y += v.y; acc.z += v.z; acc.w += v.w;
    }
    reinterpret_cast<float4*>(rst)[node * 16 + g] = acc;
}

// ===========================================================================
// Weight prep: fragment-linear bf16 buffers for mfma_f32_32x32x16_bf16.
// wf[0..31]   : W1^T A-frags, frag(ht,ks) = wf[ht*4+ks],  ht<8, ks<4
//               lane l elem j = W1[16*ks + 8*(l>>5) + j][32*ht + (l&31)]
// wf[32..63]  : W2^T A-frags, frag(dt,ks) = wf[32+dt*16+ks], dt<2, ks<16
//               lane l elem j = W2[16*ks + 8*(l>>5) + j][32*dt + (l&31)]
// ===========================================================================
__global__ void prep_weights_kernel(const float* __restrict__ W1,
                                    const float* __restrict__ W2,
                                    bf16x8* __restrict__ wf) {
    int fid  = blockIdx.x;        // 0..63
    int lane = threadIdx.x;       // 0..63
    int g = lane >> 5, c = lane & 31;
    bf16x8 v;
    if (fid < 32) {
        int ht = fid >> 2, ks = fid & 3;
        const float* col = W1 + (32 * ht + c);
        int k0 = 16 * ks + 8 * g;
#pragma unroll
        for (int j = 0; j < 8; ++j) v[j] = (__bf16)col[(size_t)(k0 + j) * H];
    } else {
        int f = fid - 32;
        int dt = f >> 4, ks = f & 15;
        const float* col = W2 + (32 * dt + c);
        int k0 = 16 * ks + 8 * g;
#pragma unroll
        for (int j = 0; j < 8; ++j) v[j] = (__bf16)col[(size_t)(k0 + j) * D];
    }
    wf[fid * 64 + lane] = v;
}

// ===========================================================================
// Fused MFMA MLP: out = relu(rst @ W1 + b1) @ W2 + b2
// Computed transposed: h^T = W1^T @ rst^T ; out^T = W2^T @ h^T.
// Per wave: 32 nodes. h never touches LDS: layer1 C-frags are converted to
// layer2 B-frags with bf16 packs + lane32 half-swap (T12 pattern).
// C/D layout (verified m74/m101): col = lane&31, row = (reg&3)+8*(reg>>2)+4*(lane>>5)
// ===========================================================================
__global__ __launch_bounds__(512, 4) void mlp_mfma_kernel(
        const float* __restrict__ rst, const bf16x8* __restrict__ wf,
        const float* __restrict__ b1, const float* __restrict__ b2,
        float* __restrict__ out, int n, int ntiles) {
    __shared__ bf16x8 swf[64 * 64];   // 64 KiB
    __shared__ float sb1[H];
    __shared__ float sb2[D];

    for (int i = threadIdx.x; i < 64 * 64; i += 512) swf[i] = wf[i];
    if (threadIdx.x < H) sb1[threadIdx.x] = b1[threadIdx.x];
    if (threadIdx.x < D) sb2[threadIdx.x] = b2[threadIdx.x];
    __syncthreads();

    int lane = threadIdx.x & 63;
    int wid  = threadIdx.x >> 6;
    int g = lane >> 5, c = lane & 31;

    int tile = blockIdx.x * 8 + wid;
    if (tile >= ntiles) return;
    int node = tile * 32 + c;
    bool valid = node < n;
    int nodeC = valid ? node : (n - 1);

    // B1 frags: rst^T. lane l: col=node, k = 16*ks + 8*g + j (8 contiguous f32)
    bf16x8 bfr[4];
    const float* rrow = rst + (size_t)nodeC * D + 8 * g;
#pragma unroll
    for (int ks = 0; ks < 4; ++ks) {
        float4 lo = *reinterpret_cast<const float4*>(rrow + 16 * ks);
        float4 hi = *reinterpret_cast<const float4*>(rrow + 16 * ks + 4);
        bf16x8 v;
        v[0] = (__bf16)lo.x; v[1] = (__bf16)lo.y; v[2] = (__bf16)lo.z; v[3] = (__bf16)lo.w;
        v[4] = (__bf16)hi.x; v[5] = (__bf16)hi.y; v[6] = (__bf16)hi.z; v[7] = (__bf16)hi.w;
        bfr[ks] = v;
    }

    f32x16 acc2_0 = {};
    f32x16 acc2_1 = {};

#pragma unroll
    for (int ht = 0; ht < 8; ++ht) {
        // ---- layer 1: acc1 = W1^T(ht) @ rst^T  (32 hidden x 32 nodes) ----
        f32x16 a1 = {};
#pragma unroll
        for (int ks = 0; ks < 4; ++ks)
            a1 = __builtin_amdgcn_mfma_f32_32x32x16_bf16(
                     swf[(ht * 4 + ks) * 64 + lane], bfr[ks], a1, 0, 0, 0);

        // bias + relu.  reg r -> hidden = 32*ht + (r&3) + 8*(r>>2) + 4*g
        float hv[16];
#pragma unroll
        for (int q = 0; q < 4; ++q) {
            float4 bq = *reinterpret_cast<const float4*>(&sb1[32 * ht + 8 * q + 4 * g]);
            hv[4 * q + 0] = fmaxf(a1[4 * q + 0] + bq.x, 0.0f);
            hv[4 * q + 1] = fmaxf(a1[4 * q + 1] + bq.y, 0.0f);
            hv[4 * q + 2] = fmaxf(a1[4 * q + 2] + bq.z, 0.0f);
            hv[4 * q + 3] = fmaxf(a1[4 * q + 3] + bq.w, 0.0f);
        }

        // ---- layer 2: for ks2 = 2*ht (regs 0..7) and 2*ht+1 (regs 8..15):
        // build h^T B-frag in-register, accumulate into both d-tiles ----
#pragma unroll
        for (int half = 0; half < 2; ++half) {
            const float* hs = hv + 8 * half;
            unsigned plo0 = pack_bf16x2(hs[0], hs[1]);
            unsigned plo1 = pack_bf16x2(hs[2], hs[3]);
            unsigned phi0 = pack_bf16x2(hs[4], hs[5]);
            unsigned phi1 = pack_bf16x2(hs[6], hs[7]);
            unsigned f0, f2, f1, f3;
            lane32_swap(plo0, phi0, f0, f2);
            lane32_swap(plo1, phi1, f1, f3);
            uint4v fr = { f0, f1, f2, f3 };
            bf16x8 b2f = __builtin_bit_cast(bf16x8, fr);
            int ks2 = 2 * ht + half;
            acc2_0 = __builtin_amdgcn_mfma_f32_32x32x16_bf16(
                         swf[(32 + 0 * 16 + ks2) * 64 + lane], b2f, acc2_0, 0, 0, 0);
            acc2_1 = __builtin_amdgcn_mfma_f32_32x32x16_bf16(
                         swf[(32 + 1 * 16 + ks2) * 64 + lane], b2f, acc2_1, 0, 0, 0);
        }
    }

    // ---- epilogue: out[node][d] = acc2 + b2, d = 32*dt + 8*q + 4*g + i ----
    if (!valid) return;
    float* orow = out + (size_t)node * D;
#pragma unroll
    for (int dt = 0; dt < 2; ++dt) {
        const f32x16& a = dt ? acc2_1 : acc2_0;
#pragma unroll
        for (int q = 0; q < 4; ++q) {
            int d0 = 32 * dt + 8 * q + 4 * g;
            float4 bq = *reinterpret_cast<const float4*>(&sb2[d0]);
            float4 v;
            v.x = a[4 * q + 0] + bq.x;
            v.y = a[4 * q + 1] + bq.y;
            v.z = a[4 * q + 2] + bq.z;
            v.w = a[4 * q + 3] + bq.w;
            *reinterpret_cast<float4*>(orow + d0) = v;
        }
    }
}

// ===========================================================================
// Fallbacks (small workspace): atomic scatter + fp32 VALU MLP
// ===========================================================================
__global__ void copy_feat_kernel(const float* __restrict__ feat,
                                 float* __restrict__ rst, int n4) {
    int i = blockIdx.x * blockDim.x + threadIdx.x;
    if (i < n4) {
        reinterpret_cast<float4*>(rst)[i] =
            reinterpret_cast<const float4*>(feat)[i];
    }
}

__global__ void scatter_add_kernel(const float* __restrict__ feat,
                                   const int* __restrict__ src,
                                   const int* __restrict__ dst,
                                   float* rst, int E) {
    int gid = blockIdx.x * blockDim.x + threadIdx.x;
    int e = gid >> 4;
    if (e >= E) return;
    int d4 = (gid & 15) << 2;
    int s = src[e];
    int t = dst[e];
    float4 v = *reinterpret_cast<const float4*>(&feat[s * D + d4]);
    float* p = &rst[t * D + d4];
    atomicAdd(p + 0, v.x);
    atomicAdd(p + 1, v.y);
    atomicAdd(p + 2, v.z);
    atomicAdd(p + 3, v.w);
}

__global__ __launch_bounds__(512) void mlp_valu_kernel(
        const float* rst,
        const float* __restrict__ W1, const float* __restrict__ b1,
        const float* __restrict__ W2, const float* __restrict__ b2,
        float* out, int n) {
    __shared__ float sW1t[H * D];
    __shared__ float sW2 [H * D];
    __shared__ float sb1[H];
    __shared__ float sb2[D];

    for (int i = threadIdx.x; i < D * H; i += 512) {
        int d = i >> 8;
        int j = i & (H - 1);
        sW1t[j * D + d] = W1[i];
        sW2[i] = W2[i];
    }
    if (threadIdx.x < H) sb1[threadIdx.x] = b1[threadIdx.x];
    if (threadIdx.x < D) sb2[threadIdx.x] = b2[threadIdx.x];
    __syncthreads();

    int node = blockIdx.x * 512 + threadIdx.x;
    if (node >= n) return;

    float x[D];
    const float4* xr = reinterpret_cast<const float4*>(&rst[node * D]);
#pragma unroll
    for (int d4 = 0; d4 < D / 4; ++d4) {
        float4 v = xr[d4];
        x[d4 * 4 + 0] = v.x; x[d4 * 4 + 1] = v.y;
        x[d4 * 4 + 2] = v.z; x[d4 * 4 + 3] = v.w;
    }
    float acc[D];
#pragma unroll
    for (int d = 0; d < D; ++d) acc[d] = sb2[d];
    for (int j = 0; j < H; ++j) {
        float h = sb1[j];
        const float4* w1 = reinterpret_cast<const float4*>(&sW1t[j * D]);
#pragma unroll
        for (int d4 = 0; d4 < D / 4; ++d4) {
            float4 w = w1[d4];
            h += x[d4 * 4 + 0] * w.x + x[d4 * 4 + 1] * w.y +
                 x[d4 * 4 + 2] * w.z + x[d4 * 4 + 3] * w.w;
        }
        h = fmaxf(h, 0.0f);
        const float4* w2 = reinterpret_cast<const float4*>(&sW2[j * D]);
#pragma unroll
        for (int d4 = 0; d4 < D / 4; ++d4) {
            float4 w = w2[d4];
            acc[d4 * 4 + 0] += h * w.x; acc[d4 * 4 + 1] += h * w.y;
            acc[d4 * 4 + 2] += h * w.z; acc[d4 * 4 + 3] += h * w.w;
        }
    }
    float4* op = reinterpret_cast<float4*>(&out[node * D]);
#pragma unroll
    for (int d4 = 0; d4 < D / 4; ++d4) {
        float4 v;
        v.x = acc[d4 * 4 + 0]; v.y = acc[d4 * 4 + 1];
        v.z = acc[d4 * 4 + 2]; v.w = acc[d4 * 4 + 3];
        op[d4] = v;
    }
}

// ===========================================================================
extern "C" void kernel_launch(void* const* d_in, const int* in_sizes, int n_in,
                              void* d_out, int out_size, void* d_ws, size_t ws_size,
                              hipStream_t stream) {
    const float* feat = (const float*)d_in[0];
    const float* W1   = (const float*)d_in[1];
    const float* b1   = (const float*)d_in[2];
    const float* W2   = (const float*)d_in[3];
    const float* b2   = (const float*)d_in[4];
    const int*   src  = (const int*)d_in[5];
    const int*   dst  = (const int*)d_in[6];
    float* buf = (float*)d_out;   // rst, then out (in place)

    int n = in_sizes[0] / D;
    int E = in_sizes[5];

    const size_t wfBytes = 64 * 64 * sizeof(bf16x8);   // 64 KiB
    bool haveWf = ws_size >= wfBytes;

    int nb = (n + 1023) / 1024;
    size_t needInts = (size_t)(n + (n + 1) + n + ((nb + 255) & ~255) + E) * sizeof(int);
    bool haveCsr = ws_size >= wfBytes + needInts;

    bf16x8* wf = (bf16x8*)d_ws;
    if (haveWf) prep_weights_kernel<<<64, 64, 0, stream>>>(W1, W2, wf);

    if (haveCsr) {
        int* deg    = (int*)((char*)d_ws + wfBytes);
        int* off    = deg + n;
        int* cursor = off + (n + 1);
        int* bsums  = cursor + n;
        int* csr    = bsums + ((nb + 255) & ~255);

        zero_int_kernel<<<(n + 255) / 256, 256, 0, stream>>>(deg, n);
        hist_kernel<<<(E + 255) / 256, 256, 0, stream>>>(dst, deg, E);
        scan_blocks_kernel<<<nb, 256, 0, stream>>>(deg, off, bsums, n);
        scan_sums_kernel<<<1, 256, 0, stream>>>(bsums, nb);
        scan_finish_kernel<<<(n + 255) / 256, 256, 0, stream>>>(off, cursor, bsums, n, E);
        fill_kernel<<<(E + 255) / 256, 256, 0, stream>>>(src, dst, cursor, csr, E);

        int gthreads = n * 16;
        gather_kernel<<<(gthreads + 255) / 256, 256, 0, stream>>>(feat, off, csr, buf, n);
    } else {
        int n4 = n * D / 4;
        copy_feat_kernel<<<(n4 + 255) / 256, 256, 0, stream>>>(feat, buf, n4);
        int threads = E * 16;
        scatter_add_kernel<<<(threads + 255) / 256, 256, 0, stream>>>(feat, src, dst, buf, E);
    }

    if (haveWf) {
        int ntiles = (n + 31) / 32;
        int blocks = (ntiles + 7) / 8;
        mlp_mfma_kernel<<<blocks, 512, 0, stream>>>(buf, wf, b1, b2, buf, n, ntiles);
    } else {
        mlp_valu_kernel<<<(n + 511) / 512, 512, 0, stream>>>(buf, W1, b1, W2, b2, buf, n);
    }
}